// Round 7
// baseline (448.469 us; speedup 1.0000x reference)
//
#include <hip/hip_runtime.h>
#include <hip/hip_bf16.h>

#define S_LEN 4096
#define DMODEL 1024
#define NHEADS 16
#define HDIM 64

typedef __bf16 bf16_8 __attribute__((ext_vector_type(8)));
typedef float f32x4 __attribute__((ext_vector_type(4)));
typedef unsigned short u16;
typedef unsigned int u32;

__device__ __forceinline__ u16 f2bf(float f) {
    union { float f; u32 u; } v; v.f = f;
    u32 r = v.u + 0x7FFFu + ((v.u >> 16) & 1u);
    return (u16)(r >> 16);
}
__device__ __forceinline__ float bf2f(u16 h) {
    union { u32 u; float f; } v; v.u = ((u32)h) << 16;
    return v.f;
}

// async global->LDS, 16B per lane; dest = wave-uniform base + lane*16
__device__ __forceinline__ void gld16(const u16* g, u16* l) {
    __builtin_amdgcn_global_load_lds(
        (const __attribute__((address_space(1))) u32*)g,
        (__attribute__((address_space(3))) u32*)l, 16, 0, 0);
}

// ---------------- fp32 -> bf16 conversion ----------------
__global__ void cvt_kernel(const float* __restrict__ src, u16* __restrict__ dst, int n) {
    int i = (blockIdx.x * blockDim.x + threadIdx.x) * 4;
    int stride = gridDim.x * blockDim.x * 4;
    for (; i < n; i += stride) {
        float4 v = *reinterpret_cast<const float4*>(src + i);
        ushort4 o;
        o.x = f2bf(v.x); o.y = f2bf(v.y); o.z = f2bf(v.z); o.w = f2bf(v.w);
        *reinterpret_cast<ushort4*>(dst + i) = o;
    }
}

// fused 4-weight cvt: blockIdx.y selects the (1M-element) weight matrix
__global__ void cvt4_kernel(const float* __restrict__ s0, const float* __restrict__ s1,
                            const float* __restrict__ s2, const float* __restrict__ s3,
                            u16* __restrict__ d0, u16* __restrict__ d1,
                            u16* __restrict__ d2, u16* __restrict__ d3, int n) {
    const float* src = blockIdx.y == 0 ? s0 : blockIdx.y == 1 ? s1 : blockIdx.y == 2 ? s2 : s3;
    u16* dst = blockIdx.y == 0 ? d0 : blockIdx.y == 1 ? d1 : blockIdx.y == 2 ? d2 : d3;
    int i = (blockIdx.x * blockDim.x + threadIdx.x) * 4;
    int stride = gridDim.x * blockDim.x * 4;
    for (; i < n; i += stride) {
        float4 v = *reinterpret_cast<const float4*>(src + i);
        ushort4 o;
        o.x = f2bf(v.x); o.y = f2bf(v.y); o.z = f2bf(v.z); o.w = f2bf(v.w);
        *reinterpret_cast<ushort4*>(dst + i) = o;
    }
}

// ---------------- RoPE tables ----------------
__global__ void rope_table_kernel(float* __restrict__ cosT, float* __restrict__ sinT) {
    int idx = blockIdx.x * blockDim.x + threadIdx.x;
    if (idx >= S_LEN * 32) return;
    int s = idx >> 5, i = idx & 31;
    float inv = expf(-((float)(2 * i) / (float)HDIM) * logf(10000.0f));
    float fr = (float)s * inv;
    cosT[idx] = cosf(fr);
    sinT[idx] = sinf(fr);
}

// ---------------- GEMM: C = A(MxK) @ B(NxK)^T + bias  (2-phase double-buffered) ----------------
// BM=BN=128, BK=32, 256 thr (4 waves 2x2), per-wave 64x64 = acc[4][4]
// Pipeline: stage(k+1) -> compute(k) -> barrier  (loads in flight under compute)
// MODE 0: three outputs (Q,K,V) by blockIdx.z, bf16 (H,S,hd), RoPE fused for z<2
// MODE 1: single fp32 output (S,D) + bias
template<int MODE>
__global__ __launch_bounds__(256) void gemm_kernel(
    const u16* __restrict__ A,
    const u16* __restrict__ B0, const u16* __restrict__ B1, const u16* __restrict__ B2,
    const float* __restrict__ bias0, const float* __restrict__ bias1, const float* __restrict__ bias2,
    u16* __restrict__ dst0, u16* __restrict__ dst1, u16* __restrict__ dst2,
    float* __restrict__ outF,
    const float* __restrict__ cosT, const float* __restrict__ sinT)
{
    const int bm = blockIdx.y * 128;
    const int bn = blockIdx.x * 128;
    const u16* B = B0; const float* bias = bias0; u16* dst = dst0;
    bool rope = (MODE == 0);
    if (MODE == 0) {
        if (blockIdx.z == 1)      { B = B1; bias = bias1; dst = dst1; }
        else if (blockIdx.z == 2) { B = B2; bias = bias2; dst = dst2; rope = false; }
    }
    __shared__ __align__(16) u16 As[2][128 * 32];
    __shared__ __align__(16) u16 Bs[2][128 * 32];
    const int tid = threadIdx.x, lane = tid & 63, wid = tid >> 6;
    const int wm = (wid >> 1) * 64, wn = (wid & 1) * 64;
    // staging: linear row-major [128][32]
    const int srow = wid * 16 + (lane >> 2);
    const int scol = (lane & 3) * 8;
    const u16* Aptr = A + (size_t)(bm + srow) * DMODEL + scol;
    const u16* Bptr = B + (size_t)(bn + srow) * DMODEL + scol;

    f32x4 acc[4][4] = {};

    auto stage = [&](int buf, int k0) {
        gld16(Aptr + k0, As[buf] + wid * 512);
        gld16(Aptr + (size_t)64 * DMODEL + k0, As[buf] + 2048 + wid * 512);
        gld16(Bptr + k0, Bs[buf] + wid * 512);
        gld16(Bptr + (size_t)64 * DMODEL + k0, Bs[buf] + 2048 + wid * 512);
    };
    auto compute = [&](int buf) {
        bf16_8 af[4], bfv[4];
        #pragma unroll
        for (int i = 0; i < 4; i++) {
            af[i]  = *(const bf16_8*)&As[buf][(wm + i * 16 + (lane & 15)) * 32 + (lane >> 4) * 8];
            bfv[i] = *(const bf16_8*)&Bs[buf][(wn + i * 16 + (lane & 15)) * 32 + (lane >> 4) * 8];
        }
        #pragma unroll
        for (int i = 0; i < 4; i++)
            #pragma unroll
            for (int j = 0; j < 4; j++)
                acc[i][j] = __builtin_amdgcn_mfma_f32_16x16x32_bf16(af[i], bfv[j], acc[i][j], 0, 0, 0);
    };

    stage(0, 0);
    __syncthreads();
    int cur = 0;
    for (int k0 = 32; k0 < DMODEL; k0 += 32) {
        stage(cur ^ 1, k0);
        compute(cur);
        __syncthreads();
        cur ^= 1;
    }
    compute(cur);

    #pragma unroll
    for (int mi = 0; mi < 4; mi++) {
        #pragma unroll
        for (int ni = 0; ni < 2; ni++) {
            const int d1 = ni * 16 + (lane & 15);
            const int col1 = bn + wn + d1;
            const float b1 = bias[col1], b2 = bias[col1 + 32];
            #pragma unroll
            for (int r = 0; r < 4; r++) {
                const int row = bm + wm + mi * 16 + (lane >> 4) * 4 + r;
                float x1 = acc[mi][ni][r] + b1;
                float x2 = acc[mi][ni + 2][r] + b2;
                if (MODE == 0) {
                    float y1 = x1, y2 = x2;
                    if (rope) {
                        float c = cosT[(row << 5) + d1], s = sinT[(row << 5) + d1];
                        y1 = x1 * c - x2 * s;
                        y2 = x2 * c + x1 * s;
                    }
                    const int h = (bn + wn) >> 6;
                    dst[((size_t)h * S_LEN + row) * HDIM + d1]      = f2bf(y1);
                    dst[((size_t)h * S_LEN + row) * HDIM + d1 + 32] = f2bf(y2);
                } else {
                    outF[(size_t)row * DMODEL + col1]      = x1;
                    outF[(size_t)row * DMODEL + col1 + 32] = x2;
                }
            }
        }
    }
}

// ---------------- causal flash attention (double-buffered K/V) ----------------
// grid (S/128, H) with bx reversed (big blocks first); 4 waves, wave w owns q-rows [q0, q0+32)
// K in LDS: linear-swizzled, slot = (d>>3)^(kv&7), staged via global_load_lds w/ pre-swizzled src
// V in LDS: transposed Vt[d][kv], slot = (kv>>3)^(d&7), reg-staged issue-early/write-late
// Pipeline per tile t: {issue K-gld(t+1), V-reg-load(t+1)} -> compute(t) -> barrier(A) ->
//                      write Vt(t+1) -> barrier(B)
// Softmax in exp2 domain: Q pre-scaled by 0.125*log2(e)
__global__ __launch_bounds__(256) void attn_kernel(
    const u16* __restrict__ Q, const u16* __restrict__ K, const u16* __restrict__ V,
    u16* __restrict__ AO)
{
    const int bxr = (int)(gridDim.x - 1 - blockIdx.x);
    const int h = blockIdx.y;
    const int tid = threadIdx.x, lane = tid & 63, wid = tid >> 6;
    const int q0 = bxr * 128 + wid * 32;
    const u16* Qh = Q + (size_t)h * S_LEN * HDIM;
    const u16* Kh = K + (size_t)h * S_LEN * HDIM;
    const u16* Vh = V + (size_t)h * S_LEN * HDIM;

    __shared__ __align__(16) u16 Ks[2][64 * 64];
    __shared__ __align__(16) u16 Vt[2][64 * 64];
    __shared__ __align__(16) u16 Ps[4][32][72];

    // Q fragments, pre-scaled by 0.125*log2(e) (exp2 softmax domain)
    const float QSCALE = 0.125f * 1.44269504f;
    bf16_8 qf[2][2];
    #pragma unroll
    for (int m = 0; m < 2; m++)
        #pragma unroll
        for (int db = 0; db < 2; db++) {
            const u16* qp = Qh + (size_t)(q0 + m * 16 + (lane & 15)) * HDIM + db * 32 + (lane >> 4) * 8;
            union { uint4 q; u16 u[8]; } t; t.q = *(const uint4*)qp;
            union { u16 u[8]; bf16_8 b; } ob;
            #pragma unroll
            for (int j = 0; j < 8; j++) ob.u[j] = f2bf(bf2f(t.u[j]) * QSCALE);
            qf[m][db] = ob.b;
        }

    // K staging per-lane fixed offsets
    const int kvl0 = wid * 8 + (lane >> 3);
    const int koff0 = kvl0 * 64 + (((lane & 7) ^ (kvl0 & 7)) << 3);
    const int kvl1 = kvl0 + 32;
    const int koff1 = kvl1 * 64 + (((lane & 7) ^ (kvl1 & 7)) << 3);
    // V staging
    const int vkv0 = tid >> 3;        // 0..31
    const int vd0 = (tid & 7) * 8;
    const int vst = tid & 7;

    f32x4 o[2][4] = {};
    float mrow[2][4], lrow[2][4];
    #pragma unroll
    for (int m = 0; m < 2; m++)
        #pragma unroll
        for (int r = 0; r < 4; r++) { mrow[m][r] = -__builtin_inff(); lrow[m][r] = 0.f; }

    union { u16 u[8]; bf16_8 b; } onesu;
    #pragma unroll
    for (int j = 0; j < 8; j++) onesu.u[j] = 0x3F80;
    const bf16_8 ones = onesu.b;

    const int ntiles = bxr * 2 + 2;
    const int ndiag = ntiles - 2;

    union { uint4 q; u16 u[8]; } va, vb;

    // ---- prologue: stage tile 0 ----
    gld16(Kh + koff0, &Ks[0][wid * 512]);
    gld16(Kh + koff1, &Ks[0][2048 + wid * 512]);
    va.q = *(const uint4*)(Vh + tid * 8);
    vb.q = *(const uint4*)(Vh + 2048 + tid * 8);
    #pragma unroll
    for (int jj = 0; jj < 8; jj++) {
        const int j = (jj + vst) & 7;
        Vt[0][(vd0 + j) * 64 + (((vkv0 >> 3) ^ j) << 3) + (vkv0 & 7)] = va.u[j];
        Vt[0][(vd0 + j) * 64 + ((((vkv0 + 32) >> 3) ^ j) << 3) + (vkv0 & 7)] = vb.u[j];
    }
    __syncthreads();   // Ks[0] (vmcnt drain) + Vt[0] visible

    int cur = 0;
    for (int t = 0; t < ntiles; t++) {
        const int nxt = cur ^ 1;
        const bool pf = (t + 1 < ntiles);
        if (pf) {
            const u16* Kg = Kh + (size_t)(t + 1) * 4096;
            const u16* Vg = Vh + (size_t)(t + 1) * 4096;
            gld16(Kg + koff0, &Ks[nxt][wid * 512]);
            gld16(Kg + koff1, &Ks[nxt][2048 + wid * 512]);
            va.q = *(const uint4*)(Vg + tid * 8);
            vb.q = *(const uint4*)(Vg + 2048 + tid * 8);
        }

        // QK^T: sc[m][nt] over 32 q-rows x 64 kv
        f32x4 sc[2][4];
        #pragma unroll
        for (int m = 0; m < 2; m++)
            #pragma unroll
            for (int nt = 0; nt < 4; nt++) sc[m][nt] = (f32x4){0.f, 0.f, 0.f, 0.f};
        #pragma unroll
        for (int nt = 0; nt < 4; nt++) {
            const int kvr = nt * 16 + (lane & 15);
            #pragma unroll
            for (int db = 0; db < 2; db++) {
                bf16_8 kf = *(const bf16_8*)&Ks[cur][kvr * 64 + (((db * 4 + (lane >> 4)) ^ (lane & 7)) << 3)];
                sc[0][nt] = __builtin_amdgcn_mfma_f32_16x16x32_bf16(qf[0][db], kf, sc[0][nt], 0, 0, 0);
                sc[1][nt] = __builtin_amdgcn_mfma_f32_16x16x32_bf16(qf[1][db], kf, sc[1][nt], 0, 0, 0);
            }
        }
        // causal mask: only the two diagonal tiles
        if (t >= ndiag) {
            #pragma unroll
            for (int m = 0; m < 2; m++)
                #pragma unroll
                for (int nt = 0; nt < 4; nt++) {
                    const int kj = t * 64 + nt * 16 + (lane & 15);
                    #pragma unroll
                    for (int r = 0; r < 4; r++) {
                        const int qi = q0 + m * 16 + (lane >> 4) * 4 + r;
                        if (kj > qi) sc[m][nt][r] = -1e30f;
                    }
                }
        }
        // row max (reduce over nt then over lane&15)
        float pmax[2][4], fs[2][4];
        #pragma unroll
        for (int m = 0; m < 2; m++)
            #pragma unroll
            for (int r = 0; r < 4; r++)
                pmax[m][r] = fmaxf(fmaxf(sc[m][0][r], sc[m][1][r]), fmaxf(sc[m][2][r], sc[m][3][r]));
        #pragma unroll
        for (int off = 1; off < 16; off <<= 1)
            #pragma unroll
            for (int m = 0; m < 2; m++)
                #pragma unroll
                for (int r = 0; r < 4; r++)
                    pmax[m][r] = fmaxf(pmax[m][r], __shfl_xor(pmax[m][r], off, 64));
        #pragma unroll
        for (int m = 0; m < 2; m++)
            #pragma unroll
            for (int r = 0; r < 4; r++) {
                const float mn = fmaxf(mrow[m][r], pmax[m][r]);
                fs[m][r] = exp2f(mrow[m][r] - mn);
                mrow[m][r] = mn;
            }
        // P -> LDS (bf16), and rescale o
        #pragma unroll
        for (int m = 0; m < 2; m++)
            #pragma unroll
            for (int nt = 0; nt < 4; nt++)
                #pragma unroll
                for (int r = 0; r < 4; r++) {
                    const float p = exp2f(sc[m][nt][r] - mrow[m][r]);
                    Ps[wid][m * 16 + (lane >> 4) * 4 + r][nt * 16 + (lane & 15)] = f2bf(p);
                }
        #pragma unroll
        for (int m = 0; m < 2; m++)
            #pragma unroll
            for (int dt = 0; dt < 4; dt++)
                #pragma unroll
                for (int r = 0; r < 4; r++) o[m][dt][r] *= fs[m][r];
        asm volatile("" ::: "memory");
        // PV + rowsum-via-MFMA(ones)
        f32x4 ls[2] = {};
        #pragma unroll
        for (int ks = 0; ks < 2; ks++) {
            bf16_8 pa[2];
            #pragma unroll
            for (int m = 0; m < 2; m++)
                pa[m] = *(const bf16_8*)&Ps[wid][m * 16 + (lane & 15)][ks * 32 + (lane >> 4) * 8];
            ls[0] = __builtin_amdgcn_mfma_f32_16x16x32_bf16(pa[0], ones, ls[0], 0, 0, 0);
            ls[1] = __builtin_amdgcn_mfma_f32_16x16x32_bf16(pa[1], ones, ls[1], 0, 0, 0);
            #pragma unroll
            for (int dt = 0; dt < 4; dt++) {
                const int d = dt * 16 + (lane & 15);
                bf16_8 vf = *(const bf16_8*)&Vt[cur][d * 64 + (((ks * 4 + (lane >> 4)) ^ (lane & 7)) << 3)];
                o[0][dt] = __builtin_amdgcn_mfma_f32_16x16x32_bf16(pa[0], vf, o[0][dt], 0, 0, 0);
                o[1][dt] = __builtin_amdgcn_mfma_f32_16x16x32_bf16(pa[1], vf, o[1][dt], 0, 0, 0);
            }
        }
        #pragma unroll
        for (int m = 0; m < 2; m++)
            #pragma unroll
            for (int r = 0; r < 4; r++)
                lrow[m][r] = lrow[m][r] * fs[m][r] + ls[m][r];

        __syncthreads();   // (A): done reading Ks[cur]/Vt[cur]; drains K(t+1) gld + V regs
        if (pf) {
            #pragma unroll
            for (int jj = 0; jj < 8; jj++) {
                const int j = (jj + vst) & 7;
                Vt[nxt][(vd0 + j) * 64 + (((vkv0 >> 3) ^ j) << 3) + (vkv0 & 7)] = va.u[j];
                Vt[nxt][(vd0 + j) * 64 + ((((vkv0 + 32) >> 3) ^ j) << 3) + (vkv0 & 7)] = vb.u[j];
            }
            __syncthreads(); // (B): Vt[nxt] visible for t+1
        }
        cur = nxt;
    }
    // epilogue: normalize, store (S, D) bf16
    #pragma unroll
    for (int m = 0; m < 2; m++)
        #pragma unroll
        for (int dt = 0; dt < 4; dt++)
            #pragma unroll
            for (int r = 0; r < 4; r++) {
                const int qi = q0 + m * 16 + (lane >> 4) * 4 + r;
                const int d = dt * 16 + (lane & 15);
                AO[(size_t)qi * DMODEL + h * HDIM + d] = f2bf(o[m][dt][r] / lrow[m][r]);
            }
}

extern "C" void kernel_launch(void* const* d_in, const int* in_sizes, int n_in,
                              void* d_out, int out_size, void* d_ws, size_t ws_size,
                              hipStream_t stream) {
    const float* x  = (const float*)d_in[0];
    const float* Wq = (const float*)d_in[1];
    const float* bq = (const float*)d_in[2];
    const float* Wk = (const float*)d_in[3];
    const float* bk = (const float*)d_in[4];
    const float* Wv = (const float*)d_in[5];
    const float* bv = (const float*)d_in[6];
    const float* Wo = (const float*)d_in[7];
    const float* bo = (const float*)d_in[8];
    float* out = (float*)d_out;

    const size_t SZ_X = (size_t)S_LEN * DMODEL;   // 4M elements
    const size_t SZ_W = (size_t)DMODEL * DMODEL;  // 1M elements

    char* ws = (char*)d_ws;
    u16* xb  = (u16*)ws;                ws += SZ_X * 2;
    u16* Wqb = (u16*)ws;                ws += SZ_W * 2;
    u16* Wkb = (u16*)ws;                ws += SZ_W * 2;
    u16* Wvb = (u16*)ws;                ws += SZ_W * 2;
    u16* Wob = (u16*)ws;                ws += SZ_W * 2;
    u16* Qb  = (u16*)ws;                ws += SZ_X * 2;
    u16* Kb  = (u16*)ws;                ws += SZ_X * 2;
    u16* Vb  = (u16*)ws;                ws += SZ_X * 2;
    u16* AO  = (u16*)ws;                ws += SZ_X * 2;
    float* cosT = (float*)ws;           ws += (size_t)S_LEN * 32 * 4;
    float* sinT = (float*)ws;

    cvt_kernel<<<dim3(2048), dim3(256), 0, stream>>>(x, xb, (int)SZ_X);
    cvt4_kernel<<<dim3(1024, 4), dim3(256), 0, stream>>>(Wq, Wk, Wv, Wo, Wqb, Wkb, Wvb, Wob, (int)SZ_W);
    rope_table_kernel<<<dim3((S_LEN * 32) / 256), dim3(256), 0, stream>>>(cosT, sinT);

    gemm_kernel<0><<<dim3(DMODEL / 128, S_LEN / 128, 3), dim3(256), 0, stream>>>(
        xb, Wqb, Wkb, Wvb, bq, bk, bv, Qb, Kb, Vb, nullptr, cosT, sinT);

    attn_kernel<<<dim3(S_LEN / 128, NHEADS), dim3(256), 0, stream>>>(Qb, Kb, Vb, AO);

    gemm_kernel<1><<<dim3(DMODEL / 128, S_LEN / 128, 1), dim3(256), 0, stream>>>(
        AO, Wob, Wob, Wob, bo, bo, bo, nullptr, nullptr, nullptr, out, cosT, sinT);
}

// Round 8
// 415.423 us; speedup vs baseline: 1.0795x; 1.0795x over previous
//
#include <hip/hip_runtime.h>
#include <hip/hip_bf16.h>

#define S_LEN 4096
#define DMODEL 1024
#define NHEADS 16
#define HDIM 64

typedef __bf16 bf16_8 __attribute__((ext_vector_type(8)));
typedef float f32x4 __attribute__((ext_vector_type(4)));
typedef unsigned short u16;
typedef unsigned int u32;

__device__ __forceinline__ u16 f2bf(float f) {
    union { float f; u32 u; } v; v.f = f;
    u32 r = v.u + 0x7FFFu + ((v.u >> 16) & 1u);
    return (u16)(r >> 16);
}
__device__ __forceinline__ float bf2f(u16 h) {
    union { u32 u; float f; } v; v.u = ((u32)h) << 16;
    return v.f;
}

// async global->LDS, 16B per lane; dest = wave-uniform base + lane*16
__device__ __forceinline__ void gld16(const u16* g, u16* l) {
    __builtin_amdgcn_global_load_lds(
        (const __attribute__((address_space(1))) u32*)g,
        (__attribute__((address_space(3))) u32*)l, 16, 0, 0);
}

// ---------------- fp32 -> bf16 conversion ----------------
__global__ void cvt_kernel(const float* __restrict__ src, u16* __restrict__ dst, int n) {
    int i = (blockIdx.x * blockDim.x + threadIdx.x) * 4;
    int stride = gridDim.x * blockDim.x * 4;
    for (; i < n; i += stride) {
        float4 v = *reinterpret_cast<const float4*>(src + i);
        ushort4 o;
        o.x = f2bf(v.x); o.y = f2bf(v.y); o.z = f2bf(v.z); o.w = f2bf(v.w);
        *reinterpret_cast<ushort4*>(dst + i) = o;
    }
}

// fused 4-weight cvt
__global__ void cvt4_kernel(const float* __restrict__ s0, const float* __restrict__ s1,
                            const float* __restrict__ s2, const float* __restrict__ s3,
                            u16* __restrict__ d0, u16* __restrict__ d1,
                            u16* __restrict__ d2, u16* __restrict__ d3, int n) {
    const float* src = blockIdx.y == 0 ? s0 : blockIdx.y == 1 ? s1 : blockIdx.y == 2 ? s2 : s3;
    u16* dst = blockIdx.y == 0 ? d0 : blockIdx.y == 1 ? d1 : blockIdx.y == 2 ? d2 : d3;
    int i = (blockIdx.x * blockDim.x + threadIdx.x) * 4;
    int stride = gridDim.x * blockDim.x * 4;
    for (; i < n; i += stride) {
        float4 v = *reinterpret_cast<const float4*>(src + i);
        ushort4 o;
        o.x = f2bf(v.x); o.y = f2bf(v.y); o.z = f2bf(v.z); o.w = f2bf(v.w);
        *reinterpret_cast<ushort4*>(dst + i) = o;
    }
}

// ---------------- RoPE tables ----------------
__global__ void rope_table_kernel(float* __restrict__ cosT, float* __restrict__ sinT) {
    int idx = blockIdx.x * blockDim.x + threadIdx.x;
    if (idx >= S_LEN * 32) return;
    int s = idx >> 5, i = idx & 31;
    float inv = expf(-((float)(2 * i) / (float)HDIM) * logf(10000.0f));
    float fr = (float)s * inv;
    cosT[idx] = cosf(fr);
    sinT[idx] = sinf(fr);
}

// ---------------- GEMM: C = A(MxK) @ B(NxK)^T + bias ----------------
// BM=64, BN=128, BK=32, 256 thr (4 waves 2x2), per-wave 32x64 = acc[2][4]
// 2-phase double-buffered: stage(k+1) -> compute(k) -> barrier
// MODE 0: three outputs (Q,K,V) by blockIdx.z, bf16 (H,S,hd), RoPE fused for z<2
// MODE 1: single fp32 output (S,D) + bias
template<int MODE>
__global__ __launch_bounds__(256) void gemm_kernel(
    const u16* __restrict__ A,
    const u16* __restrict__ B0, const u16* __restrict__ B1, const u16* __restrict__ B2,
    const float* __restrict__ bias0, const float* __restrict__ bias1, const float* __restrict__ bias2,
    u16* __restrict__ dst0, u16* __restrict__ dst1, u16* __restrict__ dst2,
    float* __restrict__ outF,
    const float* __restrict__ cosT, const float* __restrict__ sinT)
{
    const int bm = blockIdx.y * 64;
    const int bn = blockIdx.x * 128;
    const u16* B = B0; const float* bias = bias0; u16* dst = dst0;
    bool rope = (MODE == 0);
    if (MODE == 0) {
        if (blockIdx.z == 1)      { B = B1; bias = bias1; dst = dst1; }
        else if (blockIdx.z == 2) { B = B2; bias = bias2; dst = dst2; rope = false; }
    }
    __shared__ __align__(16) u16 As[2][64 * 32];
    __shared__ __align__(16) u16 Bs[2][128 * 32];
    const int tid = threadIdx.x, lane = tid & 63, wid = tid >> 6;
    const int wm = (wid >> 1) * 32, wn = (wid & 1) * 64;
    // staging: linear row-major [rows][32]
    const int srow = wid * 16 + (lane >> 2);  // 0..63
    const int scol = (lane & 3) * 8;
    const u16* Aptr = A + (size_t)(bm + srow) * DMODEL + scol;
    const u16* Bptr = B + (size_t)(bn + srow) * DMODEL + scol;

    f32x4 acc[2][4] = {};

    auto stage = [&](int buf, int k0) {
        gld16(Aptr + k0, As[buf] + wid * 512);
        gld16(Bptr + k0, Bs[buf] + wid * 512);
        gld16(Bptr + (size_t)64 * DMODEL + k0, Bs[buf] + 2048 + wid * 512);
    };
    auto compute = [&](int buf) {
        bf16_8 af[2], bfv[4];
        #pragma unroll
        for (int i = 0; i < 2; i++)
            af[i] = *(const bf16_8*)&As[buf][(wm + i * 16 + (lane & 15)) * 32 + (lane >> 4) * 8];
        #pragma unroll
        for (int j = 0; j < 4; j++)
            bfv[j] = *(const bf16_8*)&Bs[buf][(wn + j * 16 + (lane & 15)) * 32 + (lane >> 4) * 8];
        #pragma unroll
        for (int i = 0; i < 2; i++)
            #pragma unroll
            for (int j = 0; j < 4; j++)
                acc[i][j] = __builtin_amdgcn_mfma_f32_16x16x32_bf16(af[i], bfv[j], acc[i][j], 0, 0, 0);
    };

    stage(0, 0);
    __syncthreads();
    int cur = 0;
    for (int k0 = 32; k0 < DMODEL; k0 += 32) {
        stage(cur ^ 1, k0);
        compute(cur);
        __syncthreads();
        cur ^= 1;
    }
    compute(cur);

    #pragma unroll
    for (int mi = 0; mi < 2; mi++) {
        #pragma unroll
        for (int ni = 0; ni < 2; ni++) {
            const int d1 = ni * 16 + (lane & 15);
            const int col1 = bn + wn + d1;
            const float b1 = bias[col1], b2 = bias[col1 + 32];
            #pragma unroll
            for (int r = 0; r < 4; r++) {
                const int row = bm + wm + mi * 16 + (lane >> 4) * 4 + r;
                float x1 = acc[mi][ni][r] + b1;
                float x2 = acc[mi][ni + 2][r] + b2;
                if (MODE == 0) {
                    float y1 = x1, y2 = x2;
                    if (rope) {
                        float c = cosT[(row << 5) + d1], s = sinT[(row << 5) + d1];
                        y1 = x1 * c - x2 * s;
                        y2 = x2 * c + x1 * s;
                    }
                    const int h = (bn + wn) >> 6;
                    dst[((size_t)h * S_LEN + row) * HDIM + d1]      = f2bf(y1);
                    dst[((size_t)h * S_LEN + row) * HDIM + d1 + 32] = f2bf(y2);
                } else {
                    outF[(size_t)row * DMODEL + col1]      = x1;
                    outF[(size_t)row * DMODEL + col1 + 32] = x2;
                }
            }
        }
    }
}

// ---------------- causal flash attention (swapped QK^T: S^T in registers) ----------------
// grid (S/128, H), bx reversed; 4 waves, wave w owns q-rows [q0, q0+32)
// QK^T computed as mfma(K, Q) -> S^T: lane holds ONE q (lane&15 per m), 16 kv per tile.
// Row-max: 15 in-reg fmax + 2 shfl hops. Softmax state scalar per m.
// P -> LDS as packed uint2 (4 bf16/write); PV = mfma(Vt, P) -> O^T; rowsum via ones-MFMA.
// K in LDS swizzled (slot=(d>>3)^(kv&7)) via global_load_lds w/ pre-swizzled src; dbuf.
// V transposed in LDS Vt[d][kv], slot=(kv>>3)^(d&7); reg-staged issue-early/write-late; dbuf.
__global__ __launch_bounds__(256) void attn_kernel(
    const u16* __restrict__ Q, const u16* __restrict__ K, const u16* __restrict__ V,
    u16* __restrict__ AO)
{
    const int bxr = (int)(gridDim.x - 1 - blockIdx.x);
    const int h = blockIdx.y;
    const int tid = threadIdx.x, lane = tid & 63, wid = tid >> 6;
    const int q0 = bxr * 128 + wid * 32;
    const u16* Qh = Q + (size_t)h * S_LEN * HDIM;
    const u16* Kh = K + (size_t)h * S_LEN * HDIM;
    const u16* Vh = V + (size_t)h * S_LEN * HDIM;

    __shared__ __align__(16) u16 Ks[2][64 * 64];
    __shared__ __align__(16) u16 Vt[2][64 * 64];
    __shared__ __align__(16) u16 Ps[4][32][72];

    // Q fragments (B-operand), pre-scaled by 0.125*log2(e)
    const float QSCALE = 0.125f * 1.44269504f;
    bf16_8 qf[2][2];
    #pragma unroll
    for (int m = 0; m < 2; m++)
        #pragma unroll
        for (int db = 0; db < 2; db++) {
            const u16* qp = Qh + (size_t)(q0 + m * 16 + (lane & 15)) * HDIM + db * 32 + (lane >> 4) * 8;
            union { uint4 q; u16 u[8]; } t; t.q = *(const uint4*)qp;
            union { u16 u[8]; bf16_8 b; } ob;
            #pragma unroll
            for (int j = 0; j < 8; j++) ob.u[j] = f2bf(bf2f(t.u[j]) * QSCALE);
            qf[m][db] = ob.b;
        }

    // K staging per-lane fixed offsets
    const int kvl0 = wid * 8 + (lane >> 3);
    const int koff0 = kvl0 * 64 + (((lane & 7) ^ (kvl0 & 7)) << 3);
    const int kvl1 = kvl0 + 32;
    const int koff1 = kvl1 * 64 + (((lane & 7) ^ (kvl1 & 7)) << 3);
    // V staging
    const int vkv0 = tid >> 3;        // 0..31
    const int vd0 = (tid & 7) * 8;
    const int vst = tid & 7;

    f32x4 o[2][4] = {};
    float mrow[2], lrow[2];
    #pragma unroll
    for (int m = 0; m < 2; m++) { mrow[m] = -__builtin_inff(); lrow[m] = 0.f; }

    union { u16 u[8]; bf16_8 b; } onesu;
    #pragma unroll
    for (int j = 0; j < 8; j++) onesu.u[j] = 0x3F80;
    const bf16_8 ones = onesu.b;

    const int ntiles = bxr * 2 + 2;
    const int ndiag = ntiles - 2;

    union { uint4 q; u16 u[8]; } va, vb;

    // ---- prologue: stage tile 0 ----
    gld16(Kh + koff0, &Ks[0][wid * 512]);
    gld16(Kh + koff1, &Ks[0][2048 + wid * 512]);
    va.q = *(const uint4*)(Vh + tid * 8);
    vb.q = *(const uint4*)(Vh + 2048 + tid * 8);
    #pragma unroll
    for (int jj = 0; jj < 8; jj++) {
        const int j = (jj + vst) & 7;
        Vt[0][(vd0 + j) * 64 + (((vkv0 >> 3) ^ j) << 3) + (vkv0 & 7)] = va.u[j];
        Vt[0][(vd0 + j) * 64 + ((((vkv0 + 32) >> 3) ^ j) << 3) + (vkv0 & 7)] = vb.u[j];
    }
    __syncthreads();   // Ks[0] (vmcnt drain) + Vt[0] visible

    int cur = 0;
    for (int t = 0; t < ntiles; t++) {
        const int nxt = cur ^ 1;
        const bool pf = (t + 1 < ntiles);
        if (pf) {
            const u16* Kg = Kh + (size_t)(t + 1) * 4096;
            const u16* Vg = Vh + (size_t)(t + 1) * 4096;
            gld16(Kg + koff0, &Ks[nxt][wid * 512]);
            gld16(Kg + koff1, &Ks[nxt][2048 + wid * 512]);
            va.q = *(const uint4*)(Vg + tid * 8);
            vb.q = *(const uint4*)(Vg + 2048 + tid * 8);
        }

        // QK^T swapped: st[m][nt] = S^T (rows kv, cols q)
        f32x4 st[2][4];
        #pragma unroll
        for (int m = 0; m < 2; m++)
            #pragma unroll
            for (int nt = 0; nt < 4; nt++) st[m][nt] = (f32x4){0.f, 0.f, 0.f, 0.f};
        #pragma unroll
        for (int nt = 0; nt < 4; nt++) {
            const int kvr = nt * 16 + (lane & 15);
            #pragma unroll
            for (int db = 0; db < 2; db++) {
                bf16_8 kf = *(const bf16_8*)&Ks[cur][kvr * 64 + (((db * 4 + (lane >> 4)) ^ (lane & 7)) << 3)];
                st[0][nt] = __builtin_amdgcn_mfma_f32_16x16x32_bf16(kf, qf[0][db], st[0][nt], 0, 0, 0);
                st[1][nt] = __builtin_amdgcn_mfma_f32_16x16x32_bf16(kf, qf[1][db], st[1][nt], 0, 0, 0);
            }
        }
        // causal mask: only the two diagonal tiles. kv = t*64+nt*16+(lane>>4)*4+r; q = q0+m*16+(lane&15)
        if (t >= ndiag) {
            #pragma unroll
            for (int m = 0; m < 2; m++) {
                const int qi = q0 + m * 16 + (lane & 15);
                #pragma unroll
                for (int nt = 0; nt < 4; nt++) {
                    const int kvb = t * 64 + nt * 16 + ((lane >> 4) << 2);
                    #pragma unroll
                    for (int r = 0; r < 4; r++)
                        if (kvb + r > qi) st[m][nt][r] = -1e30f;
                }
            }
        }
        // row max: in-register over 16 kv, then 2 shfl hops across lane-groups
        float fs[2];
        #pragma unroll
        for (int m = 0; m < 2; m++) {
            float pm = -__builtin_inff();
            #pragma unroll
            for (int nt = 0; nt < 4; nt++) {
                float a = fmaxf(st[m][nt][0], st[m][nt][1]);
                float b = fmaxf(st[m][nt][2], st[m][nt][3]);
                pm = fmaxf(pm, fmaxf(a, b));
            }
            pm = fmaxf(pm, __shfl_xor(pm, 16, 64));
            pm = fmaxf(pm, __shfl_xor(pm, 32, 64));
            const float mn = fmaxf(mrow[m], pm);
            fs[m] = exp2f(mrow[m] - mn);
            mrow[m] = mn;
        }
        // P -> LDS packed (4 bf16 per uint2 write)
        #pragma unroll
        for (int m = 0; m < 2; m++) {
            u16* prow = &Ps[wid][m * 16 + (lane & 15)][(lane >> 4) << 2];
            #pragma unroll
            for (int nt = 0; nt < 4; nt++) {
                union { u16 u[4]; uint2 v; } pk;
                #pragma unroll
                for (int r = 0; r < 4; r++)
                    pk.u[r] = f2bf(exp2f(st[m][nt][r] - mrow[m]));
                *reinterpret_cast<uint2*>(prow + nt * 16) = pk.v;
            }
        }
        // rescale o
        #pragma unroll
        for (int m = 0; m < 2; m++)
            #pragma unroll
            for (int dt = 0; dt < 4; dt++)
                #pragma unroll
                for (int r = 0; r < 4; r++) o[m][dt][r] *= fs[m];
        asm volatile("" ::: "memory");
        // PV (O^T = Vt x P) + rowsum-via-MFMA(ones)
        f32x4 ls[2] = {};
        #pragma unroll
        for (int ks = 0; ks < 2; ks++) {
            bf16_8 pa[2];
            #pragma unroll
            for (int m = 0; m < 2; m++)
                pa[m] = *(const bf16_8*)&Ps[wid][m * 16 + (lane & 15)][ks * 32 + (lane >> 4) * 8];
            ls[0] = __builtin_amdgcn_mfma_f32_16x16x32_bf16(ones, pa[0], ls[0], 0, 0, 0);
            ls[1] = __builtin_amdgcn_mfma_f32_16x16x32_bf16(ones, pa[1], ls[1], 0, 0, 0);
            #pragma unroll
            for (int dt = 0; dt < 4; dt++) {
                bf16_8 vf = *(const bf16_8*)&Vt[cur][(dt * 16 + (lane & 15)) * 64 + (((ks * 4 + (lane >> 4)) ^ (lane & 7)) << 3)];
                o[0][dt] = __builtin_amdgcn_mfma_f32_16x16x32_bf16(vf, pa[0], o[0][dt], 0, 0, 0);
                o[1][dt] = __builtin_amdgcn_mfma_f32_16x16x32_bf16(vf, pa[1], o[1][dt], 0, 0, 0);
            }
        }
        #pragma unroll
        for (int m = 0; m < 2; m++)
            lrow[m] = lrow[m] * fs[m] + ls[m][0];

        __syncthreads();   // (A): done reading Ks[cur]/Vt[cur]; drains K(t+1) gld + V regs
        if (pf) {
            #pragma unroll
            for (int jj = 0; jj < 8; jj++) {
                const int j = (jj + vst) & 7;
                Vt[nxt][(vd0 + j) * 64 + (((vkv0 >> 3) ^ j) << 3) + (vkv0 & 7)] = va.u[j];
                Vt[nxt][(vd0 + j) * 64 + ((((vkv0 + 32) >> 3) ^ j) << 3) + (vkv0 & 7)] = vb.u[j];
            }
            __syncthreads(); // (B): Vt[nxt] visible for t+1
        }
        cur = nxt;
    }
    // epilogue: normalize, store (S, D) bf16, vectorized ushort4
    #pragma unroll
    for (int m = 0; m < 2; m++) {
        const float inv = 1.0f / lrow[m];
        const int qi = q0 + m * 16 + (lane & 15);
        u16* aorow = AO + (size_t)qi * DMODEL + h * HDIM + ((lane >> 4) << 2);
        #pragma unroll
        for (int dt = 0; dt < 4; dt++) {
            union { u16 u[4]; ushort4 s; } ov;
            #pragma unroll
            for (int r = 0; r < 4; r++)
                ov.u[r] = f2bf(o[m][dt][r] * inv);
            *reinterpret_cast<ushort4*>(aorow + dt * 16) = ov.s;
        }
    }
}

extern "C" void kernel_launch(void* const* d_in, const int* in_sizes, int n_in,
                              void* d_out, int out_size, void* d_ws, size_t ws_size,
                              hipStream_t stream) {
    const float* x  = (const float*)d_in[0];
    const float* Wq = (const float*)d_in[1];
    const float* bq = (const float*)d_in[2];
    const float* Wk = (const float*)d_in[3];
    const float* bk = (const float*)d_in[4];
    const float* Wv = (const float*)d_in[5];
    const float* bv = (const float*)d_in[6];
    const float* Wo = (const float*)d_in[7];
    const float* bo = (const float*)d_in[8];
    float* out = (float*)d_out;

    const size_t SZ_X = (size_t)S_LEN * DMODEL;   // 4M elements
    const size_t SZ_W = (size_t)DMODEL * DMODEL;  // 1M elements

    char* ws = (char*)d_ws;
    u16* xb  = (u16*)ws;                ws += SZ_X * 2;
    u16* Wqb = (u16*)ws;                ws += SZ_W * 2;
    u16* Wkb = (u16*)ws;                ws += SZ_W * 2;
    u16* Wvb = (u16*)ws;                ws += SZ_W * 2;
    u16* Wob = (u16*)ws;                ws += SZ_W * 2;
    u16* Qb  = (u16*)ws;                ws += SZ_X * 2;
    u16* Kb  = (u16*)ws;                ws += SZ_X * 2;
    u16* Vb  = (u16*)ws;                ws += SZ_X * 2;
    u16* AO  = (u16*)ws;                ws += SZ_X * 2;
    float* cosT = (float*)ws;           ws += (size_t)S_LEN * 32 * 4;
    float* sinT = (float*)ws;

    cvt_kernel<<<dim3(2048), dim3(256), 0, stream>>>(x, xb, (int)SZ_X);
    cvt4_kernel<<<dim3(1024, 4), dim3(256), 0, stream>>>(Wq, Wk, Wv, Wo, Wqb, Wkb, Wvb, Wob, (int)SZ_W);
    rope_table_kernel<<<dim3((S_LEN * 32) / 256), dim3(256), 0, stream>>>(cosT, sinT);

    gemm_kernel<0><<<dim3(DMODEL / 128, S_LEN / 64, 3), dim3(256), 0, stream>>>(
        xb, Wqb, Wkb, Wvb, bq, bk, bv, Qb, Kb, Vb, nullptr, cosT, sinT);

    attn_kernel<<<dim3(S_LEN / 128, NHEADS), dim3(256), 0, stream>>>(Qb, Kb, Vb, AO);

    gemm_kernel<1><<<dim3(DMODEL / 128, S_LEN / 64, 1), dim3(256), 0, stream>>>(
        AO, Wob, Wob, Wob, bo, bo, bo, nullptr, nullptr, nullptr, out, cosT, sinT);
}

// Round 9
// 383.706 us; speedup vs baseline: 1.1688x; 1.0827x over previous
//
#include <hip/hip_runtime.h>
#include <hip/hip_bf16.h>

#define S_LEN 4096
#define DMODEL 1024
#define NHEADS 16
#define HDIM 64

typedef __bf16 bf16_8 __attribute__((ext_vector_type(8)));
typedef float f32x4 __attribute__((ext_vector_type(4)));
typedef unsigned short u16;
typedef unsigned int u32;

__device__ __forceinline__ u16 f2bf(float f) {
    union { float f; u32 u; } v; v.f = f;
    u32 r = v.u + 0x7FFFu + ((v.u >> 16) & 1u);
    return (u16)(r >> 16);
}
__device__ __forceinline__ float bf2f(u16 h) {
    union { u32 u; float f; } v; v.u = ((u32)h) << 16;
    return v.f;
}

// async global->LDS, 16B per lane; dest = wave-uniform base + lane*16
__device__ __forceinline__ void gld16(const u16* g, u16* l) {
    __builtin_amdgcn_global_load_lds(
        (const __attribute__((address_space(1))) u32*)g,
        (__attribute__((address_space(3))) u32*)l, 16, 0, 0);
}

// ---------------- fp32 -> bf16 conversion ----------------
__global__ void cvt_kernel(const float* __restrict__ src, u16* __restrict__ dst, int n) {
    int i = (blockIdx.x * blockDim.x + threadIdx.x) * 4;
    int stride = gridDim.x * blockDim.x * 4;
    for (; i < n; i += stride) {
        float4 v = *reinterpret_cast<const float4*>(src + i);
        ushort4 o;
        o.x = f2bf(v.x); o.y = f2bf(v.y); o.z = f2bf(v.z); o.w = f2bf(v.w);
        *reinterpret_cast<ushort4*>(dst + i) = o;
    }
}

// fused 4-weight cvt
__global__ void cvt4_kernel(const float* __restrict__ s0, const float* __restrict__ s1,
                            const float* __restrict__ s2, const float* __restrict__ s3,
                            u16* __restrict__ d0, u16* __restrict__ d1,
                            u16* __restrict__ d2, u16* __restrict__ d3, int n) {
    const float* src = blockIdx.y == 0 ? s0 : blockIdx.y == 1 ? s1 : blockIdx.y == 2 ? s2 : s3;
    u16* dst = blockIdx.y == 0 ? d0 : blockIdx.y == 1 ? d1 : blockIdx.y == 2 ? d2 : d3;
    int i = (blockIdx.x * blockDim.x + threadIdx.x) * 4;
    int stride = gridDim.x * blockDim.x * 4;
    for (; i < n; i += stride) {
        float4 v = *reinterpret_cast<const float4*>(src + i);
        ushort4 o;
        o.x = f2bf(v.x); o.y = f2bf(v.y); o.z = f2bf(v.z); o.w = f2bf(v.w);
        *reinterpret_cast<ushort4*>(dst + i) = o;
    }
}

// ---------------- RoPE tables ----------------
__global__ void rope_table_kernel(float* __restrict__ cosT, float* __restrict__ sinT) {
    int idx = blockIdx.x * blockDim.x + threadIdx.x;
    if (idx >= S_LEN * 32) return;
    int s = idx >> 5, i = idx & 31;
    float inv = expf(-((float)(2 * i) / (float)HDIM) * logf(10000.0f));
    float fr = (float)s * inv;
    cosT[idx] = cosf(fr);
    sinT[idx] = sinf(fr);
}

// ---------------- GEMM: C = A(MxK) @ B(NxK)^T + bias ----------------
// BM=64, BN=128, BK=64, 256 thr (4 waves 2x2), per-wave 32x64 = acc[2][4]
// 2-phase double-buffered, 16 K-steps. LDS XOR-swizzled (slot = colblk ^ (row&7)),
// written via gld16 with pre-swizzled global source col.
// MODE 0: three outputs (Q,K,V) by blockIdx.z, bf16 (H,S,hd), RoPE fused for z<2
// MODE 1: single fp32 output (S,D) + bias
template<int MODE>
__global__ __launch_bounds__(256) void gemm_kernel(
    const u16* __restrict__ A,
    const u16* __restrict__ B0, const u16* __restrict__ B1, const u16* __restrict__ B2,
    const float* __restrict__ bias0, const float* __restrict__ bias1, const float* __restrict__ bias2,
    u16* __restrict__ dst0, u16* __restrict__ dst1, u16* __restrict__ dst2,
    float* __restrict__ outF,
    const float* __restrict__ cosT, const float* __restrict__ sinT)
{
    const int bm = blockIdx.y * 64;
    const int bn = blockIdx.x * 128;
    const u16* B = B0; const float* bias = bias0; u16* dst = dst0;
    bool rope = (MODE == 0);
    if (MODE == 0) {
        if (blockIdx.z == 1)      { B = B1; bias = bias1; dst = dst1; }
        else if (blockIdx.z == 2) { B = B2; bias = bias2; dst = dst2; rope = false; }
    }
    __shared__ __align__(16) u16 As[2][64 * 64];
    __shared__ __align__(16) u16 Bs[2][128 * 64];
    const int tid = threadIdx.x, lane = tid & 63, wid = tid >> 6;
    const int wm = (wid >> 1) * 32, wn = (wid & 1) * 64;
    // staging: each gld16 site covers 32 rows (8/wave); source col pre-swizzled
    const int arow = wid * 8 + (lane >> 3);                    // 0..31 per site
    const int acolsw = (((lane & 7) ^ (arow & 7)) << 3);       // row&7 invariant across +32-row sites
    const u16* Aptr = A + (size_t)(bm + arow) * DMODEL + acolsw;
    const u16* Bptr = B + (size_t)(bn + arow) * DMODEL + acolsw;

    f32x4 acc[2][4] = {};

    auto stage = [&](int buf, int k0) {
        gld16(Aptr + k0, As[buf] + wid * 512);
        gld16(Aptr + (size_t)32 * DMODEL + k0, As[buf] + 2048 + wid * 512);
        gld16(Bptr + k0, Bs[buf] + wid * 512);
        gld16(Bptr + (size_t)32 * DMODEL + k0, Bs[buf] + 2048 + wid * 512);
        gld16(Bptr + (size_t)64 * DMODEL + k0, Bs[buf] + 4096 + wid * 512);
        gld16(Bptr + (size_t)96 * DMODEL + k0, Bs[buf] + 6144 + wid * 512);
    };
    auto compute = [&](int buf) {
        #pragma unroll
        for (int kk = 0; kk < 2; kk++) {
            bf16_8 af[2], bfv[4];
            #pragma unroll
            for (int i = 0; i < 2; i++) {
                const int row = wm + i * 16 + (lane & 15);
                const int cb = (kk * 4 + (lane >> 4)) ^ (row & 7);
                af[i] = *(const bf16_8*)&As[buf][row * 64 + cb * 8];
            }
            #pragma unroll
            for (int j = 0; j < 4; j++) {
                const int row = wn + j * 16 + (lane & 15);
                const int cb = (kk * 4 + (lane >> 4)) ^ (row & 7);
                bfv[j] = *(const bf16_8*)&Bs[buf][row * 64 + cb * 8];
            }
            #pragma unroll
            for (int i = 0; i < 2; i++)
                #pragma unroll
                for (int j = 0; j < 4; j++)
                    acc[i][j] = __builtin_amdgcn_mfma_f32_16x16x32_bf16(af[i], bfv[j], acc[i][j], 0, 0, 0);
        }
    };

    stage(0, 0);
    __syncthreads();
    int cur = 0;
    for (int k0 = 64; k0 < DMODEL; k0 += 64) {
        stage(cur ^ 1, k0);
        compute(cur);
        __syncthreads();
        cur ^= 1;
    }
    compute(cur);

    #pragma unroll
    for (int mi = 0; mi < 2; mi++) {
        #pragma unroll
        for (int ni = 0; ni < 2; ni++) {
            const int d1 = ni * 16 + (lane & 15);
            const int col1 = bn + wn + d1;
            const float b1 = bias[col1], b2 = bias[col1 + 32];
            #pragma unroll
            for (int r = 0; r < 4; r++) {
                const int row = bm + wm + mi * 16 + (lane >> 4) * 4 + r;
                float x1 = acc[mi][ni][r] + b1;
                float x2 = acc[mi][ni + 2][r] + b2;
                if (MODE == 0) {
                    float y1 = x1, y2 = x2;
                    if (rope) {
                        float c = cosT[(row << 5) + d1], s = sinT[(row << 5) + d1];
                        y1 = x1 * c - x2 * s;
                        y2 = x2 * c + x1 * s;
                    }
                    const int h = (bn + wn) >> 6;
                    dst[((size_t)h * S_LEN + row) * HDIM + d1]      = f2bf(y1);
                    dst[((size_t)h * S_LEN + row) * HDIM + d1 + 32] = f2bf(y2);
                } else {
                    outF[(size_t)row * DMODEL + col1]      = x1;
                    outF[(size_t)row * DMODEL + col1 + 32] = x2;
                }
            }
        }
    }
}

// ---------------- causal flash attention (folded-pair, shared KV stream) ----------------
// grid (32, H). Block p handles q-tiles {jA=p, jB=63-p} (64 rows each; wave owns 16 rows of each).
// One kv pipeline t=0..jB; q-tile A also consumes tile t while t<=jA. Per-block compute
// is exactly 65 tile-units -> perfectly balanced grid.
// Swapped QK^T (S^T in regs, lane&15 = q), P packed to LDS, PV = mfma(Vt, P).
// K LDS swizzled via pre-swizzled gld16 source; V transposed reg-staged; both double-buffered.
__global__ __launch_bounds__(256) void attn_kernel(
    const u16* __restrict__ Q, const u16* __restrict__ K, const u16* __restrict__ V,
    u16* __restrict__ AO)
{
    const int jA = blockIdx.x;            // 0..31
    const int jB = 63 - jA;               // 32..63
    const int h = blockIdx.y;
    const int tid = threadIdx.x, lane = tid & 63, wid = tid >> 6;
    const int q0m[2] = { jB * 64 + wid * 16, jA * 64 + wid * 16 };  // m=0 -> jB (always), m=1 -> jA
    const u16* Qh = Q + (size_t)h * S_LEN * HDIM;
    const u16* Kh = K + (size_t)h * S_LEN * HDIM;
    const u16* Vh = V + (size_t)h * S_LEN * HDIM;

    __shared__ __align__(16) u16 Ks[2][64 * 64];
    __shared__ __align__(16) u16 Vt[2][64 * 64];
    __shared__ __align__(16) u16 Ps[4][2][16][72];

    // Q fragments (B-operand), pre-scaled by 0.125*log2(e)
    const float QSCALE = 0.125f * 1.44269504f;
    bf16_8 qf[2][2];
    #pragma unroll
    for (int m = 0; m < 2; m++)
        #pragma unroll
        for (int db = 0; db < 2; db++) {
            const u16* qp = Qh + (size_t)(q0m[m] + (lane & 15)) * HDIM + db * 32 + (lane >> 4) * 8;
            union { uint4 q; u16 u[8]; } t; t.q = *(const uint4*)qp;
            union { u16 u[8]; bf16_8 b; } ob;
            #pragma unroll
            for (int j = 0; j < 8; j++) ob.u[j] = f2bf(bf2f(t.u[j]) * QSCALE);
            qf[m][db] = ob.b;
        }

    // K staging per-lane fixed offsets
    const int kvl0 = wid * 8 + (lane >> 3);
    const int koff0 = kvl0 * 64 + (((lane & 7) ^ (kvl0 & 7)) << 3);
    const int kvl1 = kvl0 + 32;
    const int koff1 = kvl1 * 64 + (((lane & 7) ^ (kvl1 & 7)) << 3);
    // V staging
    const int vkv0 = tid >> 3;        // 0..31
    const int vd0 = (tid & 7) * 8;
    const int vst = tid & 7;

    f32x4 o[2][4] = {};
    float mrow[2], lrow[2];
    #pragma unroll
    for (int m = 0; m < 2; m++) { mrow[m] = -__builtin_inff(); lrow[m] = 0.f; }

    union { u16 u[8]; bf16_8 b; } onesu;
    #pragma unroll
    for (int j = 0; j < 8; j++) onesu.u[j] = 0x3F80;
    const bf16_8 ones = onesu.b;

    union { uint4 q; u16 u[8]; } va, vb;

    // ---- prologue: stage tile 0 ----
    gld16(Kh + koff0, &Ks[0][wid * 512]);
    gld16(Kh + koff1, &Ks[0][2048 + wid * 512]);
    va.q = *(const uint4*)(Vh + tid * 8);
    vb.q = *(const uint4*)(Vh + 2048 + tid * 8);
    #pragma unroll
    for (int jj = 0; jj < 8; jj++) {
        const int j = (jj + vst) & 7;
        Vt[0][(vd0 + j) * 64 + (((vkv0 >> 3) ^ j) << 3) + (vkv0 & 7)] = va.u[j];
        Vt[0][(vd0 + j) * 64 + ((((vkv0 + 32) >> 3) ^ j) << 3) + (vkv0 & 7)] = vb.u[j];
    }
    __syncthreads();

    int cur = 0;
    for (int t = 0; t <= jB; t++) {
        const int nxt = cur ^ 1;
        const bool pf = (t < jB);
        if (pf) {
            const u16* Kg = Kh + (size_t)(t + 1) * 4096;
            const u16* Vg = Vh + (size_t)(t + 1) * 4096;
            gld16(Kg + koff0, &Ks[nxt][wid * 512]);
            gld16(Kg + koff1, &Ks[nxt][2048 + wid * 512]);
            va.q = *(const uint4*)(Vg + tid * 8);
            vb.q = *(const uint4*)(Vg + 2048 + tid * 8);
        }
        const bool actA = (t <= jA);

        // QK^T swapped: st[m][nt] = S^T (rows kv, cols q)
        f32x4 st[2][4];
        #pragma unroll
        for (int m = 0; m < 2; m++)
            #pragma unroll
            for (int nt = 0; nt < 4; nt++) st[m][nt] = (f32x4){0.f, 0.f, 0.f, 0.f};
        #pragma unroll
        for (int nt = 0; nt < 4; nt++) {
            const int kvr = nt * 16 + (lane & 15);
            #pragma unroll
            for (int db = 0; db < 2; db++) {
                bf16_8 kf = *(const bf16_8*)&Ks[cur][kvr * 64 + (((db * 4 + (lane >> 4)) ^ (lane & 7)) << 3)];
                st[0][nt] = __builtin_amdgcn_mfma_f32_16x16x32_bf16(kf, qf[0][db], st[0][nt], 0, 0, 0);
                if (actA)
                    st[1][nt] = __builtin_amdgcn_mfma_f32_16x16x32_bf16(kf, qf[1][db], st[1][nt], 0, 0, 0);
            }
        }
        // causal mask (diagonal tiles only): m=0 at t==jB, m=1 at t==jA
        #pragma unroll
        for (int m = 0; m < 2; m++) {
            const int jm = m == 0 ? jB : jA;
            if (t == jm) {
                const int qi = q0m[m] + (lane & 15);
                #pragma unroll
                for (int nt = 0; nt < 4; nt++) {
                    const int kvb = t * 64 + nt * 16 + ((lane >> 4) << 2);
                    #pragma unroll
                    for (int r = 0; r < 4; r++)
                        if (kvb + r > qi) st[m][nt][r] = -1e30f;
                }
            }
        }
        // softmax per active m: in-reg max over 16 kv + 2 shfl hops
        float fs[2];
        #pragma unroll
        for (int m = 0; m < 2; m++) {
            if (m == 1 && !actA) continue;
            float pm = -__builtin_inff();
            #pragma unroll
            for (int nt = 0; nt < 4; nt++) {
                float a = fmaxf(st[m][nt][0], st[m][nt][1]);
                float b = fmaxf(st[m][nt][2], st[m][nt][3]);
                pm = fmaxf(pm, fmaxf(a, b));
            }
            pm = fmaxf(pm, __shfl_xor(pm, 16, 64));
            pm = fmaxf(pm, __shfl_xor(pm, 32, 64));
            const float mn = fmaxf(mrow[m], pm);
            fs[m] = exp2f(mrow[m] - mn);
            mrow[m] = mn;
            // P -> LDS packed (4 bf16 per uint2)
            u16* prow = &Ps[wid][m][lane & 15][(lane >> 4) << 2];
            #pragma unroll
            for (int nt = 0; nt < 4; nt++) {
                union { u16 u[4]; uint2 v; } pk;
                #pragma unroll
                for (int r = 0; r < 4; r++)
                    pk.u[r] = f2bf(exp2f(st[m][nt][r] - mrow[m]));
                *reinterpret_cast<uint2*>(prow + nt * 16) = pk.v;
            }
            #pragma unroll
            for (int dt = 0; dt < 4; dt++)
                #pragma unroll
                for (int r = 0; r < 4; r++) o[m][dt][r] *= fs[m];
        }
        asm volatile("" ::: "memory");
        // PV (O^T = Vt x P) + rowsum-via-MFMA(ones), per active m
        f32x4 ls[2] = {};
        #pragma unroll
        for (int ks = 0; ks < 2; ks++) {
            #pragma unroll
            for (int m = 0; m < 2; m++) {
                if (m == 1 && !actA) continue;
                bf16_8 pa = *(const bf16_8*)&Ps[wid][m][lane & 15][ks * 32 + (lane >> 4) * 8];
                ls[m] = __builtin_amdgcn_mfma_f32_16x16x32_bf16(ones, pa, ls[m], 0, 0, 0);
                #pragma unroll
                for (int dt = 0; dt < 4; dt++) {
                    bf16_8 vf = *(const bf16_8*)&Vt[cur][(dt * 16 + (lane & 15)) * 64 + (((ks * 4 + (lane >> 4)) ^ (lane & 7)) << 3)];
                    o[m][dt] = __builtin_amdgcn_mfma_f32_16x16x32_bf16(vf, pa, o[m][dt], 0, 0, 0);
                }
            }
        }
        #pragma unroll
        for (int m = 0; m < 2; m++)
            if (!(m == 1 && !actA))
                lrow[m] = lrow[m] * fs[m] + ls[m][0];

        __syncthreads();   // done reading Ks[cur]/Vt[cur]; drains K(t+1) gld + V regs
        if (pf) {
            #pragma unroll
            for (int jj = 0; jj < 8; jj++) {
                const int j = (jj + vst) & 7;
                Vt[nxt][(vd0 + j) * 64 + (((vkv0 >> 3) ^ j) << 3) + (vkv0 & 7)] = va.u[j];
                Vt[nxt][(vd0 + j) * 64 + ((((vkv0 + 32) >> 3) ^ j) << 3) + (vkv0 & 7)] = vb.u[j];
            }
            __syncthreads();
        }
        cur = nxt;
    }
    // epilogue: normalize, store (S, D) bf16, vectorized ushort4 (both q-tiles)
    #pragma unroll
    for (int m = 0; m < 2; m++) {
        const float inv = 1.0f / lrow[m];
        const int qi = q0m[m] + (lane & 15);
        u16* aorow = AO + (size_t)qi * DMODEL + h * HDIM + ((lane >> 4) << 2);
        #pragma unroll
        for (int dt = 0; dt < 4; dt++) {
            union { u16 u[4]; ushort4 s; } ov;
            #pragma unroll
            for (int r = 0; r < 4; r++)
                ov.u[r] = f2bf(o[m][dt][r] * inv);
            *reinterpret_cast<ushort4*>(aorow + dt * 16) = ov.s;
        }
    }
}

extern "C" void kernel_launch(void* const* d_in, const int* in_sizes, int n_in,
                              void* d_out, int out_size, void* d_ws, size_t ws_size,
                              hipStream_t stream) {
    const float* x  = (const float*)d_in[0];
    const float* Wq = (const float*)d_in[1];
    const float* bq = (const float*)d_in[2];
    const float* Wk = (const float*)d_in[3];
    const float* bk = (const float*)d_in[4];
    const float* Wv = (const float*)d_in[5];
    const float* bv = (const float*)d_in[6];
    const float* Wo = (const float*)d_in[7];
    const float* bo = (const float*)d_in[8];
    float* out = (float*)d_out;

    const size_t SZ_X = (size_t)S_LEN * DMODEL;   // 4M elements
    const size_t SZ_W = (size_t)DMODEL * DMODEL;  // 1M elements

    char* ws = (char*)d_ws;
    u16* xb  = (u16*)ws;                ws += SZ_X * 2;
    u16* Wqb = (u16*)ws;                ws += SZ_W * 2;
    u16* Wkb = (u16*)ws;                ws += SZ_W * 2;
    u16* Wvb = (u16*)ws;                ws += SZ_W * 2;
    u16* Wob = (u16*)ws;                ws += SZ_W * 2;
    u16* Qb  = (u16*)ws;                ws += SZ_X * 2;
    u16* Kb  = (u16*)ws;                ws += SZ_X * 2;
    u16* Vb  = (u16*)ws;                ws += SZ_X * 2;
    u16* AO  = (u16*)ws;                ws += SZ_X * 2;
    float* cosT = (float*)ws;           ws += (size_t)S_LEN * 32 * 4;
    float* sinT = (float*)ws;

    cvt_kernel<<<dim3(2048), dim3(256), 0, stream>>>(x, xb, (int)SZ_X);
    cvt4_kernel<<<dim3(1024, 4), dim3(256), 0, stream>>>(Wq, Wk, Wv, Wo, Wqb, Wkb, Wvb, Wob, (int)SZ_W);
    rope_table_kernel<<<dim3((S_LEN * 32) / 256), dim3(256), 0, stream>>>(cosT, sinT);

    gemm_kernel<0><<<dim3(DMODEL / 128, S_LEN / 64, 3), dim3(256), 0, stream>>>(
        xb, Wqb, Wkb, Wvb, bq, bk, bv, Qb, Kb, Vb, nullptr, cosT, sinT);

    attn_kernel<<<dim3(32, NHEADS), dim3(256), 0, stream>>>(Qb, Kb, Vb, AO);

    gemm_kernel<1><<<dim3(DMODEL / 128, S_LEN / 64, 1), dim3(256), 0, stream>>>(
        AO, Wob, Wob, Wob, bo, bo, bo, nullptr, nullptr, nullptr, out, cosT, sinT);
}

// Round 10
// 345.637 us; speedup vs baseline: 1.2975x; 1.1101x over previous
//
#include <hip/hip_runtime.h>
#include <hip/hip_bf16.h>

#define S_LEN 4096
#define DMODEL 1024
#define NHEADS 16
#define HDIM 64

typedef __bf16 bf16_8 __attribute__((ext_vector_type(8)));
typedef float f32x4 __attribute__((ext_vector_type(4)));
typedef unsigned short u16;
typedef unsigned int u32;

__device__ __forceinline__ u16 f2bf(float f) {
    union { float f; u32 u; } v; v.f = f;
    u32 r = v.u + 0x7FFFu + ((v.u >> 16) & 1u);
    return (u16)(r >> 16);
}
__device__ __forceinline__ float bf2f(u16 h) {
    union { u32 u; float f; } v; v.u = ((u32)h) << 16;
    return v.f;
}
// packed f32x2 -> bf16x2 (lo in [15:0], hi in [31:16])
__device__ __forceinline__ u32 cvtpk(float lo, float hi) {
    u32 r;
    asm("v_cvt_pk_bf16_f32 %0, %1, %2" : "=v"(r) : "v"(lo), "v"(hi));
    return r;
}

// async global->LDS, 16B per lane; dest = wave-uniform base + lane*16
__device__ __forceinline__ void gld16(const u16* g, u16* l) {
    __builtin_amdgcn_global_load_lds(
        (const __attribute__((address_space(1))) u32*)g,
        (__attribute__((address_space(3))) u32*)l, 16, 0, 0);
}

// ---------------- fp32 -> bf16 conversion ----------------
__global__ void cvt_kernel(const float* __restrict__ src, u16* __restrict__ dst, int n) {
    int i = (blockIdx.x * blockDim.x + threadIdx.x) * 4;
    int stride = gridDim.x * blockDim.x * 4;
    for (; i < n; i += stride) {
        float4 v = *reinterpret_cast<const float4*>(src + i);
        ushort4 o;
        o.x = f2bf(v.x); o.y = f2bf(v.y); o.z = f2bf(v.z); o.w = f2bf(v.w);
        *reinterpret_cast<ushort4*>(dst + i) = o;
    }
}

// fused 4-weight cvt
__global__ void cvt4_kernel(const float* __restrict__ s0, const float* __restrict__ s1,
                            const float* __restrict__ s2, const float* __restrict__ s3,
                            u16* __restrict__ d0, u16* __restrict__ d1,
                            u16* __restrict__ d2, u16* __restrict__ d3, int n) {
    const float* src = blockIdx.y == 0 ? s0 : blockIdx.y == 1 ? s1 : blockIdx.y == 2 ? s2 : s3;
    u16* dst = blockIdx.y == 0 ? d0 : blockIdx.y == 1 ? d1 : blockIdx.y == 2 ? d2 : d3;
    int i = (blockIdx.x * blockDim.x + threadIdx.x) * 4;
    int stride = gridDim.x * blockDim.x * 4;
    for (; i < n; i += stride) {
        float4 v = *reinterpret_cast<const float4*>(src + i);
        ushort4 o;
        o.x = f2bf(v.x); o.y = f2bf(v.y); o.z = f2bf(v.z); o.w = f2bf(v.w);
        *reinterpret_cast<ushort4*>(dst + i) = o;
    }
}

// ---------------- RoPE tables ----------------
__global__ void rope_table_kernel(float* __restrict__ cosT, float* __restrict__ sinT) {
    int idx = blockIdx.x * blockDim.x + threadIdx.x;
    if (idx >= S_LEN * 32) return;
    int s = idx >> 5, i = idx & 31;
    float inv = expf(-((float)(2 * i) / (float)HDIM) * logf(10000.0f));
    float fr = (float)s * inv;
    cosT[idx] = cosf(fr);
    sinT[idx] = sinf(fr);
}

// ---------------- GEMM: C = A(MxK) @ B(NxK)^T + bias ----------------
// BM=64, BN=128, BK=64, 256 thr (4 waves 2x2), per-wave 32x64 = acc[2][4]
// 2-phase double-buffered, 16 K-steps. LDS XOR-swizzled (slot = colblk ^ (row&7)),
// written via gld16 with pre-swizzled global source col.
template<int MODE>
__global__ __launch_bounds__(256) void gemm_kernel(
    const u16* __restrict__ A,
    const u16* __restrict__ B0, const u16* __restrict__ B1, const u16* __restrict__ B2,
    const float* __restrict__ bias0, const float* __restrict__ bias1, const float* __restrict__ bias2,
    u16* __restrict__ dst0, u16* __restrict__ dst1, u16* __restrict__ dst2,
    float* __restrict__ outF,
    const float* __restrict__ cosT, const float* __restrict__ sinT)
{
    const int bm = blockIdx.y * 64;
    const int bn = blockIdx.x * 128;
    const u16* B = B0; const float* bias = bias0; u16* dst = dst0;
    bool rope = (MODE == 0);
    if (MODE == 0) {
        if (blockIdx.z == 1)      { B = B1; bias = bias1; dst = dst1; }
        else if (blockIdx.z == 2) { B = B2; bias = bias2; dst = dst2; rope = false; }
    }
    __shared__ __align__(16) u16 As[2][64 * 64];
    __shared__ __align__(16) u16 Bs[2][128 * 64];
    const int tid = threadIdx.x, lane = tid & 63, wid = tid >> 6;
    const int wm = (wid >> 1) * 32, wn = (wid & 1) * 64;
    const int arow = wid * 8 + (lane >> 3);                    // 0..31 per site
    const int acolsw = (((lane & 7) ^ (arow & 7)) << 3);       // row&7 invariant across +32-row sites
    const u16* Aptr = A + (size_t)(bm + arow) * DMODEL + acolsw;
    const u16* Bptr = B + (size_t)(bn + arow) * DMODEL + acolsw;

    f32x4 acc[2][4] = {};

    auto stage = [&](int buf, int k0) {
        gld16(Aptr + k0, As[buf] + wid * 512);
        gld16(Aptr + (size_t)32 * DMODEL + k0, As[buf] + 2048 + wid * 512);
        gld16(Bptr + k0, Bs[buf] + wid * 512);
        gld16(Bptr + (size_t)32 * DMODEL + k0, Bs[buf] + 2048 + wid * 512);
        gld16(Bptr + (size_t)64 * DMODEL + k0, Bs[buf] + 4096 + wid * 512);
        gld16(Bptr + (size_t)96 * DMODEL + k0, Bs[buf] + 6144 + wid * 512);
    };
    auto compute = [&](int buf) {
        #pragma unroll
        for (int kk = 0; kk < 2; kk++) {
            bf16_8 af[2], bfv[4];
            #pragma unroll
            for (int i = 0; i < 2; i++) {
                const int row = wm + i * 16 + (lane & 15);
                const int cb = (kk * 4 + (lane >> 4)) ^ (row & 7);
                af[i] = *(const bf16_8*)&As[buf][row * 64 + cb * 8];
            }
            #pragma unroll
            for (int j = 0; j < 4; j++) {
                const int row = wn + j * 16 + (lane & 15);
                const int cb = (kk * 4 + (lane >> 4)) ^ (row & 7);
                bfv[j] = *(const bf16_8*)&Bs[buf][row * 64 + cb * 8];
            }
            #pragma unroll
            for (int i = 0; i < 2; i++)
                #pragma unroll
                for (int j = 0; j < 4; j++)
                    acc[i][j] = __builtin_amdgcn_mfma_f32_16x16x32_bf16(af[i], bfv[j], acc[i][j], 0, 0, 0);
        }
    };

    stage(0, 0);
    __syncthreads();
    int cur = 0;
    for (int k0 = 64; k0 < DMODEL; k0 += 64) {
        stage(cur ^ 1, k0);
        compute(cur);
        __syncthreads();
        cur ^= 1;
    }
    compute(cur);

    #pragma unroll
    for (int mi = 0; mi < 2; mi++) {
        #pragma unroll
        for (int ni = 0; ni < 2; ni++) {
            const int d1 = ni * 16 + (lane & 15);
            const int col1 = bn + wn + d1;
            const float b1 = bias[col1], b2 = bias[col1 + 32];
            #pragma unroll
            for (int r = 0; r < 4; r++) {
                const int row = bm + wm + mi * 16 + (lane >> 4) * 4 + r;
                float x1 = acc[mi][ni][r] + b1;
                float x2 = acc[mi][ni + 2][r] + b2;
                if (MODE == 0) {
                    float y1 = x1, y2 = x2;
                    if (rope) {
                        float c = cosT[(row << 5) + d1], s = sinT[(row << 5) + d1];
                        y1 = x1 * c - x2 * s;
                        y2 = x2 * c + x1 * s;
                    }
                    const int h = (bn + wn) >> 6;
                    dst[((size_t)h * S_LEN + row) * HDIM + d1]      = f2bf(y1);
                    dst[((size_t)h * S_LEN + row) * HDIM + d1 + 32] = f2bf(y2);
                } else {
                    outF[(size_t)row * DMODEL + col1]      = x1;
                    outF[(size_t)row * DMODEL + col1 + 32] = x2;
                }
            }
        }
    }
}

// ---------------- causal flash attention (folded-pair, shared KV stream) ----------------
// grid (32, H). Block p handles q-tiles {jA=p, jB=63-p}; constant 65 tile-units/block.
// Swapped QK^T (S^T in regs, lane&15 = q), P packed via v_cvt_pk_bf16_f32, PV = mfma(Vt, P).
// K LDS swizzled (slot=(d>>3)^(kv&7)) via pre-swizzled gld16 source; double-buffered.
// V: lane loads kv-row pair (2r,2r+1), packs with STATIC index, 8x ds_write_b32.
//    Vt swizzle s=(kv>>3)^(d&7)^((d>>3)&7): conflict-free writes AND 2-way (free) b128 reads.
// Defer-max (THR=8): skip o-rescale when wave-uniformly no significant new max.
__global__ __launch_bounds__(256) void attn_kernel(
    const u16* __restrict__ Q, const u16* __restrict__ K, const u16* __restrict__ V,
    u16* __restrict__ AO)
{
    const int jA = blockIdx.x;            // 0..31
    const int jB = 63 - jA;               // 32..63
    const int h = blockIdx.y;
    const int tid = threadIdx.x, lane = tid & 63, wid = tid >> 6;
    const int q0m[2] = { jB * 64 + wid * 16, jA * 64 + wid * 16 };  // m=0 -> jB, m=1 -> jA
    const u16* Qh = Q + (size_t)h * S_LEN * HDIM;
    const u16* Kh = K + (size_t)h * S_LEN * HDIM;
    const u16* Vh = V + (size_t)h * S_LEN * HDIM;

    __shared__ __align__(16) u16 Ks[2][64 * 64];
    __shared__ __align__(16) u16 Vt[2][64 * 64];
    __shared__ __align__(16) u16 Ps[4][2][16][72];

    // Q fragments (B-operand), pre-scaled by 0.125*log2(e)
    const float QSCALE = 0.125f * 1.44269504f;
    bf16_8 qf[2][2];
    #pragma unroll
    for (int m = 0; m < 2; m++)
        #pragma unroll
        for (int db = 0; db < 2; db++) {
            const u16* qp = Qh + (size_t)(q0m[m] + (lane & 15)) * HDIM + db * 32 + (lane >> 4) * 8;
            union { uint4 q; u16 u[8]; } t; t.q = *(const uint4*)qp;
            union { u16 u[8]; bf16_8 b; } ob;
            #pragma unroll
            for (int j = 0; j < 8; j++) ob.u[j] = f2bf(bf2f(t.u[j]) * QSCALE);
            qf[m][db] = ob.b;
        }

    // K staging per-lane fixed offsets
    const int kvl0 = wid * 8 + (lane >> 3);
    const int koff0 = kvl0 * 64 + (((lane & 7) ^ (kvl0 & 7)) << 3);
    const int kvl1 = kvl0 + 32;
    const int koff1 = kvl1 * 64 + (((lane & 7) ^ (kvl1 & 7)) << 3);
    // V staging: lane owns kv rows (2vr, 2vr+1), d block vc0..vc0+7
    const int vr = tid >> 3;            // 0..31
    const int vc0 = (tid & 7) * 8;
    const int vsw = (vr >> 2) ^ (tid & 7);  // s = vsw ^ j
    const int vcol = (2 * vr) & 7;

    f32x4 o[2][4] = {};
    float mrow[2], lrow[2];
    #pragma unroll
    for (int m = 0; m < 2; m++) { mrow[m] = -__builtin_inff(); lrow[m] = 0.f; }

    union { u16 u[8]; bf16_8 b; } onesu;
    #pragma unroll
    for (int j = 0; j < 8; j++) onesu.u[j] = 0x3F80;
    const bf16_8 ones = onesu.b;

    union { uint4 q; u16 u[8]; } va, vb;

    auto vwrite = [&](int buf) {
        #pragma unroll
        for (int j = 0; j < 8; j++) {
            const u32 w = (u32)va.u[j] | ((u32)vb.u[j] << 16);
            const int d = vc0 + j;
            *(u32*)&Vt[buf][d * 64 + ((vsw ^ j) << 3) + vcol] = w;
        }
    };

    // ---- prologue: stage tile 0 ----
    gld16(Kh + koff0, &Ks[0][wid * 512]);
    gld16(Kh + koff1, &Ks[0][2048 + wid * 512]);
    va.q = *(const uint4*)(Vh + (size_t)(2 * vr) * HDIM + vc0);
    vb.q = *(const uint4*)(Vh + (size_t)(2 * vr + 1) * HDIM + vc0);
    vwrite(0);
    __syncthreads();

    int cur = 0;
    for (int t = 0; t <= jB; t++) {
        const int nxt = cur ^ 1;
        const bool pf = (t < jB);
        if (pf) {
            const u16* Kg = Kh + (size_t)(t + 1) * 4096;
            const u16* Vg = Vh + (size_t)(t + 1) * 4096;
            gld16(Kg + koff0, &Ks[nxt][wid * 512]);
            gld16(Kg + koff1, &Ks[nxt][2048 + wid * 512]);
            va.q = *(const uint4*)(Vg + (size_t)(2 * vr) * HDIM + vc0);
            vb.q = *(const uint4*)(Vg + (size_t)(2 * vr + 1) * HDIM + vc0);
        }
        const bool actA = (t <= jA);

        // QK^T swapped: st[m][nt] = S^T (rows kv, cols q)
        f32x4 st[2][4];
        #pragma unroll
        for (int m = 0; m < 2; m++)
            #pragma unroll
            for (int nt = 0; nt < 4; nt++) st[m][nt] = (f32x4){0.f, 0.f, 0.f, 0.f};
        #pragma unroll
        for (int nt = 0; nt < 4; nt++) {
            const int kvr = nt * 16 + (lane & 15);
            #pragma unroll
            for (int db = 0; db < 2; db++) {
                bf16_8 kf = *(const bf16_8*)&Ks[cur][kvr * 64 + (((db * 4 + (lane >> 4)) ^ (lane & 7)) << 3)];
                st[0][nt] = __builtin_amdgcn_mfma_f32_16x16x32_bf16(kf, qf[0][db], st[0][nt], 0, 0, 0);
                if (actA)
                    st[1][nt] = __builtin_amdgcn_mfma_f32_16x16x32_bf16(kf, qf[1][db], st[1][nt], 0, 0, 0);
            }
        }
        // causal mask (diagonal tiles only): m=0 at t==jB, m=1 at t==jA
        #pragma unroll
        for (int m = 0; m < 2; m++) {
            const int jm = m == 0 ? jB : jA;
            if (t == jm) {
                const int qi = q0m[m] + (lane & 15);
                #pragma unroll
                for (int nt = 0; nt < 4; nt++) {
                    const int kvb = t * 64 + nt * 16 + ((lane >> 4) << 2);
                    #pragma unroll
                    for (int r = 0; r < 4; r++)
                        if (kvb + r > qi) st[m][nt][r] = -1e30f;
                }
            }
        }
        // softmax per active m: in-reg max over 16 kv + 2 shfl hops; defer-max THR=8
        float fs[2];
        #pragma unroll
        for (int m = 0; m < 2; m++) {
            if (m == 1 && !actA) continue;
            float pm = -__builtin_inff();
            #pragma unroll
            for (int nt = 0; nt < 4; nt++) {
                float a = fmaxf(st[m][nt][0], st[m][nt][1]);
                float b = fmaxf(st[m][nt][2], st[m][nt][3]);
                pm = fmaxf(pm, fmaxf(a, b));
            }
            pm = fmaxf(pm, __shfl_xor(pm, 16, 64));
            pm = fmaxf(pm, __shfl_xor(pm, 32, 64));
            if (__all(pm - mrow[m] <= 8.0f)) {
                fs[m] = 1.0f;    // defer: keep old max, skip rescale (P bounded by 2^8)
            } else {
                const float mn = fmaxf(mrow[m], pm);
                fs[m] = exp2f(mrow[m] - mn);
                mrow[m] = mn;
                #pragma unroll
                for (int dt = 0; dt < 4; dt++)
                    #pragma unroll
                    for (int r = 0; r < 4; r++) o[m][dt][r] *= fs[m];
            }
            // P -> LDS packed via v_cvt_pk_bf16_f32 (2 f32 -> 1 u32)
            u16* prow = &Ps[wid][m][lane & 15][(lane >> 4) << 2];
            #pragma unroll
            for (int nt = 0; nt < 4; nt++) {
                uint2 pk;
                pk.x = cvtpk(exp2f(st[m][nt][0] - mrow[m]), exp2f(st[m][nt][1] - mrow[m]));
                pk.y = cvtpk(exp2f(st[m][nt][2] - mrow[m]), exp2f(st[m][nt][3] - mrow[m]));
                *reinterpret_cast<uint2*>(prow + nt * 16) = pk;
            }
        }
        asm volatile("" ::: "memory");
        // PV (O^T = Vt x P) + rowsum-via-MFMA(ones), per active m
        f32x4 ls[2] = {};
        #pragma unroll
        for (int ks = 0; ks < 2; ks++) {
            #pragma unroll
            for (int m = 0; m < 2; m++) {
                if (m == 1 && !actA) continue;
                bf16_8 pa = *(const bf16_8*)&Ps[wid][m][lane & 15][ks * 32 + (lane >> 4) * 8];
                ls[m] = __builtin_amdgcn_mfma_f32_16x16x32_bf16(ones, pa, ls[m], 0, 0, 0);
                #pragma unroll
                for (int dt = 0; dt < 4; dt++) {
                    const int dd = dt * 16 + (lane & 15);
                    const int sv = (ks * 4 + (lane >> 4)) ^ (lane & 7) ^ ((dd >> 3) & 7);
                    bf16_8 vf = *(const bf16_8*)&Vt[cur][dd * 64 + sv * 8];
                    o[m][dt] = __builtin_amdgcn_mfma_f32_16x16x32_bf16(vf, pa, o[m][dt], 0, 0, 0);
                }
            }
        }
        #pragma unroll
        for (int m = 0; m < 2; m++)
            if (!(m == 1 && !actA))
                lrow[m] = lrow[m] * fs[m] + ls[m][0];

        __syncthreads();   // done reading Ks[cur]/Vt[cur]; drains K(t+1) gld + V regs
        if (pf) {
            vwrite(nxt);
            __syncthreads();
        }
        cur = nxt;
    }
    // epilogue: normalize, store (S, D) bf16, vectorized ushort4 (both q-tiles)
    #pragma unroll
    for (int m = 0; m < 2; m++) {
        const float inv = 1.0f / lrow[m];
        const int qi = q0m[m] + (lane & 15);
        u16* aorow = AO + (size_t)qi * DMODEL + h * HDIM + ((lane >> 4) << 2);
        #pragma unroll
        for (int dt = 0; dt < 4; dt++) {
            union { u16 u[4]; ushort4 s; } ov;
            #pragma unroll
            for (int r = 0; r < 4; r++)
                ov.u[r] = f2bf(o[m][dt][r] * inv);
            *reinterpret_cast<ushort4*>(aorow + dt * 16) = ov.s;
        }
    }
}

extern "C" void kernel_launch(void* const* d_in, const int* in_sizes, int n_in,
                              void* d_out, int out_size, void* d_ws, size_t ws_size,
                              hipStream_t stream) {
    const float* x  = (const float*)d_in[0];
    const float* Wq = (const float*)d_in[1];
    const float* bq = (const float*)d_in[2];
    const float* Wk = (const float*)d_in[3];
    const float* bk = (const float*)d_in[4];
    const float* Wv = (const float*)d_in[5];
    const float* bv = (const float*)d_in[6];
    const float* Wo = (const float*)d_in[7];
    const float* bo = (const float*)d_in[8];
    float* out = (float*)d_out;

    const size_t SZ_X = (size_t)S_LEN * DMODEL;   // 4M elements
    const size_t SZ_W = (size_t)DMODEL * DMODEL;  // 1M elements

    char* ws = (char*)d_ws;
    u16* xb  = (u16*)ws;                ws += SZ_X * 2;
    u16* Wqb = (u16*)ws;                ws += SZ_W * 2;
    u16* Wkb = (u16*)ws;                ws += SZ_W * 2;
    u16* Wvb = (u16*)ws;                ws += SZ_W * 2;
    u16* Wob = (u16*)ws;                ws += SZ_W * 2;
    u16* Qb  = (u16*)ws;                ws += SZ_X * 2;
    u16* Kb  = (u16*)ws;                ws += SZ_X * 2;
    u16* Vb  = (u16*)ws;                ws += SZ_X * 2;
    u16* AO  = (u16*)ws;                ws += SZ_X * 2;
    float* cosT = (float*)ws;           ws += (size_t)S_LEN * 32 * 4;
    float* sinT = (float*)ws;

    cvt_kernel<<<dim3(2048), dim3(256), 0, stream>>>(x, xb, (int)SZ_X);
    cvt4_kernel<<<dim3(1024, 4), dim3(256), 0, stream>>>(Wq, Wk, Wv, Wo, Wqb, Wkb, Wvb, Wob, (int)SZ_W);
    rope_table_kernel<<<dim3((S_LEN * 32) / 256), dim3(256), 0, stream>>>(cosT, sinT);

    gemm_kernel<0><<<dim3(DMODEL / 128, S_LEN / 64, 3), dim3(256), 0, stream>>>(
        xb, Wqb, Wkb, Wvb, bq, bk, bv, Qb, Kb, Vb, nullptr, cosT, sinT);

    attn_kernel<<<dim3(32, NHEADS), dim3(256), 0, stream>>>(Qb, Kb, Vb, AO);

    gemm_kernel<1><<<dim3(DMODEL / 128, S_LEN / 64, 1), dim3(256), 0, stream>>>(
        AO, Wob, Wob, Wob, bo, bo, bo, nullptr, nullptr, nullptr, out, cosT, sinT);
}